// Round 10
// baseline (368.876 us; speedup 1.0000x reference)
//
#include <hip/hip_runtime.h>
#include <hip/hip_fp16.h>

// Problem constants (from reference)
#define N0C 4096
#define E0C 16384
#define N1C 1024
#define E1C 8192
#define HC 64
#define FINC 8
#define LATC 32
#define FC 67
#define E0T (E0C + N0C)
#define E1T (E1C + N1C)
#define NBLK 256   // == CU count: all blocks co-resident even at 1 block/CU

typedef float f32x4 __attribute__((ext_vector_type(4)));
typedef _Float16 f16x8 __attribute__((ext_vector_type(8)));

struct KArgs {
  const float *x, *pos;
  const int *ei, *pei;
  const float *ppos;
  const int *keep;
  const float *l0w, *l0b, *l1w, *l1b;
  const float *c0w0, *c0b0, *c0w1, *c0b1, *c0w2, *c0b2, *c0bias;
  const float *c1w0, *c1b0, *c1w1, *c1b1, *c1w2, *c1b2, *c1bias;
  float *hc0, *tN0, *dN0, *tN1, *dN1;
  _Float16 *bC0, *bS0, *bC1, *bS1, *w1f0, *w1f1;
  int *cnt, *fill, *bar, *rp0, *rp1, *eidx0, *eidx1, *inv0, *inv1;
  float *msg, *outp;
};

struct SharedPrep { float w2s[64][69]; float xr[4][64]; };
union SharedU {
  SharedPrep prep;
  struct { _Float16 scS[4][2][64]; _Float16 scC[4][2][64]; } conv;
  struct { int wsum[4]; } scan;
  struct { float hr[4][64]; } red;
};

// grid barrier: monotone counter, target = phase*NBLK. All NBLK blocks are
// co-resident by construction (grid == CU count, >=1 block/CU guaranteed).
__device__ __forceinline__ void gsync(int* bar, int phase) {
  __syncthreads();
  if (threadIdx.x == 0) {
    __threadfence();  // agent-scope release of this block's prior writes
    __hip_atomic_fetch_add(bar, 1, __ATOMIC_RELEASE, __HIP_MEMORY_SCOPE_AGENT);
    const int target = phase * NBLK;
    while (__hip_atomic_load(bar, __ATOMIC_ACQUIRE, __HIP_MEMORY_SCOPE_AGENT) <
           target) {
      __builtin_amdgcn_s_sleep(8);
    }
  }
  __syncthreads();
}

// per-node t = w2 @ [x||pos], d = [x||pos].b2  (x row staged in xr[wave])
__device__ __forceinline__ void node_td(int lane, int wave,
    const float (*w2s)[69], const float (*xr)[64], const float* b2,
    float px, float py, float pz, float* tOut, float* dOut, int idx) {
  float tl = 0.f, ds = 0.f;
#pragma unroll 8
  for (int f = 0; f < HC; ++f) {
    float xv = xr[wave][f];
    tl = fmaf(xv, w2s[lane][f], tl);
    ds = fmaf(xv, b2[f], ds);
  }
  tl = fmaf(px, w2s[lane][64], fmaf(py, w2s[lane][65], fmaf(pz, w2s[lane][66], tl)));
  ds = fmaf(px, b2[64], fmaf(py, b2[65], fmaf(pz, b2[66], ds)));
  tOut[idx * HC + lane] = tl;
  if (lane == 0) dOut[idx] = ds;
}

// edge-parallel conv phase: persistent stride, 2-deep pipeline, tables in regs,
// msg written in CSR order via inv[].
__device__ __forceinline__ void conv_phase(
    int waveId, int nWaves, int lane, _Float16* scSw, _Float16* scCw,
    const int* ei, int E, int eTot, const float* posp,
    const float* tN, const float* dN,
    const float* kw0, const float* kb0,
    const _Float16* bC, const _Float16* bS,
    const _Float16* w1f, const float* b1,
    const int* inv, float* msg) {
  const int q = lane >> 4;
  f16x8 w1r[8], cbr[8], sbr[8];
#pragma unroll
  for (int f = 0; f < 8; ++f) {
    w1r[f] = *(const f16x8*)(w1f + ((f << 6) + lane) * 8);
    cbr[f] = *(const f16x8*)(bC + ((f << 6) + lane) * 8);
    sbr[f] = *(const f16x8*)(bS + ((f << 6) + lane) * 8);
  }
  f32x4 bbq[4];  // accumulator init = 0.1*b1[k]
#pragma unroll
  for (int ms = 0; ms < 4; ++ms) {
    f32x4 t = *(const f32x4*)(b1 + ms * 16 + q * 4);
    bbq[ms] = t * 0.1f;
  }
  const float kb0v = kb0[lane];
  const float kw0x = kw0[lane], kw0y = kw0[HC + lane], kw0z = kw0[2 * HC + lane];

  int e = waveId;
  auto stg = [&](int ee, int& sN, float& sv, float& cv, float& dv) {
    int s, d2;
    if (ee < E) { s = ei[ee]; d2 = ei[E + ee]; } else { s = ee - E; d2 = s; }
    sN = s;
    const float px = posp[s * 3], py = posp[s * 3 + 1], pz = posp[s * 3 + 2];
    const float rx = posp[d2 * 3] - px;
    const float ry = posp[d2 * 3 + 1] - py;
    const float rz = posp[d2 * 3 + 2] - pz;
    float f0 = 0.f, f1 = 0.f, f2 = 0.f;
    if (!(rx == 0.f && ry == 0.f && rz == 0.f)) {
      const float PI_F = 3.14159265358979323846f;
      float rho = sqrtf(rx * rx + ry * ry + rz * rz);
      float th = atan2f(ry, rx);
      float ratio = fminf(1.f, fmaxf(-1.f, rz / rho));
      float ph = asinf(ratio);
      f0 = rho; f1 = th / PI_F; f2 = ph / PI_F;
    }
    float base = fmaf(f0, kw0x, fmaf(f1, kw0y, fmaf(f2, kw0z, kb0v)));
    sincosf(0.1f * base, &sv, &cv);
    dv = dN[s];
  };

  int s0;
  float sv0, cv0, dv0;
  stg(e, s0, sv0, cv0, dv0);
  int buf = 0;
  scSw[lane] = (_Float16)sv0;
  scCw[lane] = (_Float16)cv0;
  __builtin_amdgcn_wave_barrier();

  while (true) {
    const int en = e + nWaves;
    const bool more = en < eTot;
    f32x4 tr[4];
    {
      const float* trp = tN + (size_t)s0 * HC;
#pragma unroll
      for (int ms = 0; ms < 4; ++ms) tr[ms] = *(const f32x4*)(trp + ms * 16 + q * 4);
    }
    const int ip = inv[e];
    int s1 = 0;
    float sv1 = 0.f, cv1 = 0.f, dv1 = 0.f;
    if (more) {
      stg(en, s1, sv1, cv1, dv1);
      scSw[(buf ^ 1) * 64 + lane] = (_Float16)sv1;
      scCw[(buf ^ 1) * 64 + lane] = (_Float16)cv1;
    }
    __builtin_amdgcn_wave_barrier();

    f32x4 acc[4][4];
#pragma unroll
    for (int ms = 0; ms < 4; ++ms)
#pragma unroll
      for (int nt = 0; nt < 4; ++nt) acc[ms][nt] = bbq[ms];
#pragma unroll
    for (int ks = 0; ks < 2; ++ks) {
      f16x8 sv8 = *(const f16x8*)&scSw[buf * 64 + ks * 32 + q * 8];
      f16x8 cv8 = *(const f16x8*)&scCw[buf * 64 + ks * 32 + q * 8];
      f16x8 bf[4];
#pragma unroll
      for (int nt = 0; nt < 4; ++nt)
        bf[nt] = sv8 * cbr[ks * 4 + nt] + cv8 * sbr[ks * 4 + nt];
#pragma unroll
      for (int ms = 0; ms < 4; ++ms)
#pragma unroll
        for (int nt = 0; nt < 4; ++nt)
          acc[ms][nt] = __builtin_amdgcn_mfma_f32_16x16x32_f16(
              w1r[ks * 4 + ms], bf[nt], acc[ms][nt], 0, 0, 0);
    }

    float snt0 = 0.f, snt1 = 0.f, snt2 = 0.f, snt3 = 0.f;
#pragma unroll
    for (int ms = 0; ms < 4; ++ms) {
#pragma unroll
      for (int r = 0; r < 4; ++r) {
        float tt = tr[ms][r];
        snt0 = fmaf(__sinf(acc[ms][0][r]), tt, snt0);
        snt1 = fmaf(__sinf(acc[ms][1][r]), tt, snt1);
        snt2 = fmaf(__sinf(acc[ms][2][r]), tt, snt2);
        snt3 = fmaf(__sinf(acc[ms][3][r]), tt, snt3);
      }
    }
    snt0 += __shfl_xor(snt0, 16, 64); snt0 += __shfl_xor(snt0, 32, 64);
    snt1 += __shfl_xor(snt1, 16, 64); snt1 += __shfl_xor(snt1, 32, 64);
    snt2 += __shfl_xor(snt2, 16, 64); snt2 += __shfl_xor(snt2, 32, 64);
    snt3 += __shfl_xor(snt3, 16, 64); snt3 += __shfl_xor(snt3, 32, 64);
    float val = (q == 0) ? snt0 : (q == 1) ? snt1 : (q == 2) ? snt2 : snt3;
    msg[(size_t)ip * HC + lane] = val + dv0;

    if (!more) break;
    e = en; s0 = s1; dv0 = dv1; buf ^= 1;
  }
}

// ---- single kernel, 8 phases, hand-rolled grid barrier (NO cooperative API) -
__global__ __launch_bounds__(256, 2) void k_mega(KArgs a) {
  __shared__ __attribute__((aligned(16))) SharedU sh;
  const int tid = threadIdx.x;
  const int bid = blockIdx.x;
  const int wave = __builtin_amdgcn_readfirstlane(tid >> 6);
  const int lane = tid & 63;
  const int waveId = bid * 4 + wave;   // 0..1023
  const int gtid = bid * 256 + tid;    // 0..65535

  // ---- P0: encoder + t/d (L0), basis/w1 frag packing, degree count ----
  {
    for (int idx = tid; idx < HC * FC; idx += 256)
      sh.prep.w2s[idx / FC][idx % FC] = a.c0w2[idx];
    __syncthreads();
#pragma unroll
    for (int i = 0; i < 4; ++i) {
      const int n = waveId + i * 1024;
      float v = a.l0b[lane];
#pragma unroll
      for (int f = 0; f < FINC; ++f) v = fmaf(a.x[n * FINC + f], a.l0w[f * HC + lane], v);
      sh.prep.xr[wave][lane] = sinf(0.01f * v);
      __builtin_amdgcn_wave_barrier();
      node_td(lane, wave, sh.prep.w2s, sh.prep.xr, a.c0b2,
              a.pos[n * 3], a.pos[n * 3 + 1], a.pos[n * 3 + 2], a.tN0, a.dN0, n);
      __builtin_amdgcn_wave_barrier();
    }
    if (gtid < 8192) {  // basis frags both levels: r=((ks*4+nt)*64+lane)*8+j
      int lvl = gtid >> 12, r = gtid & 4095;
      int fi = r >> 9, ln = (r >> 3) & 63, j = r & 7;
      int nt = fi & 3, ks = fi >> 2;
      int c = nt * 16 + (ln & 15);
      int h = ks * 32 + (ln >> 4) * 8 + j;
      const float* w = lvl ? a.c1w0 : a.c0w0;
      float s, cv;
      sincosf(0.1f * (float)c * w[3 * HC + h], &s, &cv);
      (lvl ? a.bC1 : a.bC0)[r] = (_Float16)cv;
      (lvl ? a.bS1 : a.bS0)[r] = (_Float16)s;
    } else if (gtid < 16384) {  // w1 frags (pre-scaled 0.1)
      int r0 = gtid - 8192;
      int lvl = r0 >> 12, r = r0 & 4095;
      int fi = r >> 9, ln = (r >> 3) & 63, j = r & 7;
      int ms = fi & 3, ks = fi >> 2;
      int h = ks * 32 + (ln >> 4) * 8 + j;
      int kout = ms * 16 + (ln & 15);
      const float* w = lvl ? a.c1w1 : a.c0w1;
      (lvl ? a.w1f1 : a.w1f0)[r] = (_Float16)(0.1f * w[h * HC + kout]);
    }
    if (gtid < E0T + E1T) {  // degree
      if (gtid < E0T) {
        int dst = (gtid < E0C) ? a.ei[E0C + gtid] : (gtid - E0C);
        atomicAdd(a.cnt + dst, 1);
      } else {
        int e = gtid - E0T;
        int dst = (e < E1C) ? a.pei[E1C + e] : (e - E1C);
        atomicAdd(a.cnt + N0C + dst, 1);
      }
    }
  }
  gsync(a.bar, 1);

  // ---- P1: exclusive scan (block 0: L0, block 1: L1) ----
  if (bid < 2) {
    const int n = bid ? N1C : N0C;
    const int per = bid ? 4 : 16;
    const int* c = a.cnt + (bid ? N0C : 0);
    int* rp = bid ? a.rp1 : a.rp0;
    int loc[16];
    int sum = 0;
    for (int j = 0; j < per; ++j) { loc[j] = c[tid * per + j]; sum += loc[j]; }
    int xv = sum;
#pragma unroll
    for (int off = 1; off < 64; off <<= 1) {
      int v = __shfl_up(xv, off, 64);
      if (lane >= off) xv += v;
    }
    if (lane == 63) sh.scan.wsum[wave] = xv;
    __syncthreads();
    int pre = 0;
    for (int k2 = 0; k2 < wave; ++k2) pre += sh.scan.wsum[k2];
    int incl = xv + pre;
    int base = incl - sum;
    for (int j = 0; j < per; ++j) { rp[tid * per + j] = base; base += loc[j]; }
    if (tid == 255) rp[n] = incl;
  }
  gsync(a.bar, 2);

  // ---- P2: scatter (CSR order + inverse permutation) ----
  if (gtid < E0T + E1T) {
    if (gtid < E0T) {
      int dst = (gtid < E0C) ? a.ei[E0C + gtid] : (gtid - E0C);
      int p = a.rp0[dst] + atomicAdd(a.fill + dst, 1);
      a.eidx0[p] = gtid;
      a.inv0[gtid] = p;
    } else {
      int e = gtid - E0T;
      int dst = (e < E1C) ? a.pei[E1C + e] : (e - E1C);
      int p = a.rp1[dst] + atomicAdd(a.fill + N0C + dst, 1);
      a.eidx1[p] = e;
      a.inv1[e] = p;
    }
  }
  gsync(a.bar, 3);

  // ---- P3: conv level 0 ----
  conv_phase(waveId, 1024, lane, &sh.conv.scS[wave][0][0], &sh.conv.scC[wave][0][0],
             a.ei, E0C, E0T, a.pos, a.tN0, a.dN0, a.c0w0, a.c0b0,
             a.bC0, a.bS0, a.w1f0, a.c0b1, a.inv0, a.msg);
  gsync(a.bar, 4);

  // ---- P4: reduce level 0 (4 nodes/wave) ----
#pragma unroll
  for (int i = 0; i < 4; ++i) {
    const int n = waveId + i * 1024;
    const int j0 = a.rp0[n], j1 = a.rp0[n + 1];
    const float* p = a.msg + (size_t)j0 * HC + lane;
    const int m = j1 - j0;
    float a0 = 0.f, a1 = 0.f;
    int j = 0;
    for (; j + 1 < m; j += 2) {
      a0 += p[(size_t)j * HC];
      a1 += p[(size_t)(j + 1) * HC];
    }
    if (j < m) a0 += p[(size_t)j * HC];
    a.hc0[(size_t)n * HC + lane] = sinf(0.01f * (a0 + a1 + a.c0bias[lane]));
  }
  gsync(a.bar, 5);

  // ---- P5: pool (CSR max, kept nodes) + t/d level 1 (1 node/wave) ----
  {
    for (int idx = tid; idx < HC * FC; idx += 256)
      sh.prep.w2s[idx / FC][idx % FC] = a.c1w2[idx];
    __syncthreads();
    const int i = waveId;  // < 1024
    int n = a.keep[i];
    int j0 = a.rp0[n], j1 = a.rp0[n + 1];
    float m = -INFINITY;
    for (int j = j0; j < j1; ++j) {
      int e = a.eidx0[j];
      int src = (e < E0C) ? a.ei[e] : (e - E0C);
      m = fmaxf(m, a.hc0[(size_t)src * HC + lane]);
    }
    sh.prep.xr[wave][lane] = m;
    __builtin_amdgcn_wave_barrier();
    node_td(lane, wave, sh.prep.w2s, sh.prep.xr, a.c1b2,
            a.ppos[i * 3], a.ppos[i * 3 + 1], a.ppos[i * 3 + 2], a.tN1, a.dN1, i);
  }
  gsync(a.bar, 6);

  // ---- P6: conv level 1 ----
  conv_phase(waveId, 1024, lane, &sh.conv.scS[wave][0][0], &sh.conv.scC[wave][0][0],
             a.pei, E1C, E1T, a.ppos, a.tN1, a.dN1, a.c1w0, a.c1b0,
             a.bC1, a.bS1, a.w1f1, a.c1b1, a.inv1, a.msg);
  gsync(a.bar, 7);

  // ---- P7: reduce level 1 + final linear + sin (1 node/wave) ----
  {
    const int node = waveId;  // < 1024
    const int j0 = a.rp1[node], j1 = a.rp1[node + 1];
    const float* p = a.msg + (size_t)j0 * HC + lane;
    const int m = j1 - j0;
    float a0 = 0.f, a1 = 0.f;
    int j = 0;
    for (; j + 1 < m; j += 2) {
      a0 += p[(size_t)j * HC];
      a1 += p[(size_t)(j + 1) * HC];
    }
    if (j < m) a0 += p[(size_t)j * HC];
    __syncthreads();  // sh reuse: conv -> red
    sh.red.hr[wave][lane] = sinf(0.01f * (a0 + a1 + a.c1bias[lane]));
    __builtin_amdgcn_wave_barrier();
    if (lane < LATC) {
      const float* h = sh.red.hr[wave];
      float o = a.l1b[lane];
#pragma unroll 8
      for (int c = 0; c < HC; ++c) o = fmaf(h[c], a.l1w[c * LATC + lane], o);
      a.outp[node * LATC + lane] = sinf(0.01f * o);
    }
  }
}

extern "C" void kernel_launch(void* const* d_in, const int* in_sizes, int n_in,
                              void* d_out, int out_size, void* d_ws, size_t ws_size,
                              hipStream_t stream) {
  (void)in_sizes; (void)n_in; (void)out_size; (void)ws_size;
  KArgs a;
  a.x    = (const float*)d_in[0];
  a.pos  = (const float*)d_in[1];
  a.ei   = (const int*)d_in[2];
  a.pei  = (const int*)d_in[3];
  a.ppos = (const float*)d_in[4];
  a.keep = (const int*)d_in[5];
  a.l0w  = (const float*)d_in[6];
  a.l0b  = (const float*)d_in[7];
  a.l1w  = (const float*)d_in[8];
  a.l1b  = (const float*)d_in[9];
  a.c0w0 = (const float*)d_in[10];
  a.c0b0 = (const float*)d_in[11];
  a.c0w1 = (const float*)d_in[12];
  a.c0b1 = (const float*)d_in[13];
  a.c0w2 = (const float*)d_in[14];
  a.c0b2 = (const float*)d_in[15];
  a.c0bias = (const float*)d_in[16];
  a.c1w0 = (const float*)d_in[17];
  a.c1b0 = (const float*)d_in[18];
  a.c1w1 = (const float*)d_in[19];
  a.c1b1 = (const float*)d_in[20];
  a.c1w2 = (const float*)d_in[21];
  a.c1b2 = (const float*)d_in[22];
  a.c1bias = (const float*)d_in[23];
  a.outp = (float*)d_out;

  char* p = (char*)d_ws;
  auto carve = [&](size_t bytes) -> char* {
    char* r = p;
    p += (bytes + 255) & ~(size_t)255;
    return r;
  };
  a.hc0  = (float*)carve((size_t)N0C * HC * 4);
  a.tN0  = (float*)carve((size_t)N0C * HC * 4);
  a.dN0  = (float*)carve((size_t)N0C * 4);
  a.tN1  = (float*)carve((size_t)N1C * HC * 4);
  a.dN1  = (float*)carve((size_t)N1C * 4);
  a.bC0  = (_Float16*)carve(4096 * 2);
  a.bS0  = (_Float16*)carve(4096 * 2);
  a.bC1  = (_Float16*)carve(4096 * 2);
  a.bS1  = (_Float16*)carve(4096 * 2);
  a.w1f0 = (_Float16*)carve(4096 * 2);
  a.w1f1 = (_Float16*)carve(4096 * 2);
  // cnt + fill + bar contiguous -> one memset covers all three
  a.cnt  = (int*)carve((size_t)(N0C + N1C) * 4);   // 20480 B (256-aligned)
  a.fill = (int*)carve((size_t)(N0C + N1C) * 4);   // 20480 B
  a.bar  = (int*)carve(256);                        // 256 B
  a.rp0  = (int*)carve((size_t)(N0C + 1) * 4);
  a.rp1  = (int*)carve((size_t)(N1C + 1) * 4);
  a.eidx0 = (int*)carve((size_t)E0T * 4);
  a.eidx1 = (int*)carve((size_t)E1T * 4);
  a.inv0  = (int*)carve((size_t)E0T * 4);
  a.inv1  = (int*)carve((size_t)E1T * 4);
  a.msg   = (float*)carve((size_t)E0T * HC * 4);

  hipMemsetAsync(a.cnt, 0, (size_t)(N0C + N1C) * 4 * 2 + 256, stream);

  k_mega<<<NBLK, 256, 0, stream>>>(a);
}

// Round 11
// 187.433 us; speedup vs baseline: 1.9680x; 1.9680x over previous
//
#include <hip/hip_runtime.h>
#include <hip/hip_fp16.h>

// Problem constants (from reference)
#define N0C 4096
#define E0C 16384
#define N1C 1024
#define E1C 8192
#define HC 64
#define FINC 8
#define LATC 32
#define FC 67
#define E0T (E0C + N0C)
#define E1T (E1C + N1C)

typedef float f32x4 __attribute__((ext_vector_type(4)));
typedef _Float16 f16x8 __attribute__((ext_vector_type(8)));

// ---- k_prep: blocks [0,256): encoder + per-node t/d (level 0, 4 nodes/wave)
//              blocks [256,436): basis+w1 frag packing (fp16) + degree count
__global__ __launch_bounds__(256) void k_prep(
    const float* __restrict__ x, const float* __restrict__ l0w,
    const float* __restrict__ l0b, const float* __restrict__ posp,
    const float* __restrict__ c0w2, const float* __restrict__ c0b2,
    const float* __restrict__ c0w0, const float* __restrict__ c1w0,
    const float* __restrict__ c0w1, const float* __restrict__ c1w1,
    const int* __restrict__ ei0, const int* __restrict__ ei1,
    _Float16* __restrict__ bC0, _Float16* __restrict__ bS0,
    _Float16* __restrict__ bC1, _Float16* __restrict__ bS1,
    _Float16* __restrict__ w1f0, _Float16* __restrict__ w1f1,
    int* __restrict__ cnt, float* __restrict__ tN, float* __restrict__ dN) {
  if (blockIdx.x < 256) {
    __shared__ float w2s[64][69];  // pad 67->69
    __shared__ float xr[4][64];
    const int tid = threadIdx.x;
    const int wave = __builtin_amdgcn_readfirstlane(tid >> 6), lane = tid & 63;
    for (int idx = tid; idx < HC * FC; idx += 256)
      w2s[idx / FC][idx % FC] = c0w2[idx];
    __syncthreads();
#pragma unroll
    for (int i = 0; i < 4; ++i) {
      const int n = (blockIdx.x * 4 + wave) + i * 1024;
      float a = l0b[lane];
#pragma unroll
      for (int f = 0; f < FINC; ++f) a = fmaf(x[n * FINC + f], l0w[f * HC + lane], a);
      xr[wave][lane] = sinf(0.01f * a);
      __builtin_amdgcn_wave_barrier();
      const float px = posp[n * 3], py = posp[n * 3 + 1], pz = posp[n * 3 + 2];
      float tl = 0.f, ds = 0.f;
#pragma unroll 8
      for (int f = 0; f < HC; ++f) {
        float xv = xr[wave][f];
        tl = fmaf(xv, w2s[lane][f], tl);
        ds = fmaf(xv, c0b2[f], ds);
      }
      tl = fmaf(px, w2s[lane][64], fmaf(py, w2s[lane][65], fmaf(pz, w2s[lane][66], tl)));
      ds = fmaf(px, c0b2[64], fmaf(py, c0b2[65], fmaf(pz, c0b2[66], ds)));
      tN[n * HC + lane] = tl;
      if (lane == 0) dN[n] = ds;
      __builtin_amdgcn_wave_barrier();
    }
  } else {
    int id = (blockIdx.x - 256) * 256 + threadIdx.x;
    if (id < 8192) {  // basis frags: r=((ks*4+nt)*64+lane)*8+j
      int lvl = id >> 12, r = id & 4095;
      int fi = r >> 9, lane = (r >> 3) & 63, j = r & 7;
      int nt = fi & 3, ks = fi >> 2;
      int c = nt * 16 + (lane & 15);
      int h = ks * 32 + (lane >> 4) * 8 + j;
      const float* w = lvl ? c1w0 : c0w0;
      float s, cv;
      sincosf(0.1f * (float)c * w[3 * HC + h], &s, &cv);
      (lvl ? bC1 : bC0)[r] = (_Float16)cv;
      (lvl ? bS1 : bS0)[r] = (_Float16)s;
    } else if (id < 16384) {  // w1 frags (pre-scaled by 0.1)
      int r0 = id - 8192;
      int lvl = r0 >> 12, r = r0 & 4095;
      int fi = r >> 9, lane = (r >> 3) & 63, j = r & 7;
      int ms = fi & 3, ks = fi >> 2;
      int h = ks * 32 + (lane >> 4) * 8 + j;
      int kout = ms * 16 + (lane & 15);
      const float* w = lvl ? c1w1 : c0w1;
      (lvl ? w1f1 : w1f0)[r] = (_Float16)(0.1f * w[h * HC + kout]);
    } else if (id < 16384 + E0T + E1T) {  // degree
      int r = id - 16384;
      if (r < E0T) {
        int dst = (r < E0C) ? ei0[E0C + r] : (r - E0C);
        atomicAdd(cnt + dst, 1);
      } else {
        int e = r - E0T;
        int dst = (e < E1C) ? ei1[E1C + e] : (e - E1C);
        atomicAdd(cnt + N0C + dst, 1);
      }
    }
  }
}

// ---- CSR scan, shfl-based (block 0: level0, block 1: level1) ----------------
__global__ void k_scan(const int* __restrict__ cnt, int* __restrict__ rp0,
                       int* __restrict__ rp1) {
  __shared__ int wsum[16];
  const int b = blockIdx.x;
  const int n = b ? N1C : N0C;
  const int* c = cnt + (b ? N0C : 0);
  int* rp = b ? rp1 : rp0;
  const int tid = threadIdx.x;
  const int lane = tid & 63, wid = tid >> 6;
  const int per = n >> 10;
  int loc[4];
  int sum = 0;
  for (int j = 0; j < per; ++j) { loc[j] = c[tid * per + j]; sum += loc[j]; }
  int xv = sum;
#pragma unroll
  for (int off = 1; off < 64; off <<= 1) {
    int v = __shfl_up(xv, off, 64);
    if (lane >= off) xv += v;
  }
  if (lane == 63) wsum[wid] = xv;
  __syncthreads();
  if (wid == 0) {
    int w = (lane < 16) ? wsum[lane] : 0;
#pragma unroll
    for (int off = 1; off < 16; off <<= 1) {
      int v = __shfl_up(w, off, 64);
      if (lane >= off) w += v;
    }
    if (lane < 16) wsum[lane] = w;
  }
  __syncthreads();
  int prefix = wid ? wsum[wid - 1] : 0;
  int incl = xv + prefix;
  int base = incl - sum;
  for (int j = 0; j < per; ++j) { rp[tid * per + j] = base; base += loc[j]; }
  if (tid == 1023) rp[n] = incl;
}

// ---- CSR scatter (also emits inverse permutation) ---------------------------
__global__ void k_scatter(const int* __restrict__ ei0, const int* __restrict__ ei1,
                          const int* __restrict__ rp0, const int* __restrict__ rp1,
                          int* __restrict__ fill, int* __restrict__ eidx0,
                          int* __restrict__ eidx1, int* __restrict__ inv0,
                          int* __restrict__ inv1) {
  int id = blockIdx.x * blockDim.x + threadIdx.x;
  if (id < E0T) {
    int dst = (id < E0C) ? ei0[E0C + id] : (id - E0C);
    int p = rp0[dst] + atomicAdd(fill + dst, 1);
    eidx0[p] = id;
    inv0[id] = p;
  } else if (id < E0T + E1T) {
    int e = id - E0T;
    int dst = (e < E1C) ? ei1[E1C + e] : (e - E1C);
    int p = rp1[dst] + atomicAdd(fill + N0C + dst, 1);
    eidx1[p] = e;
    inv1[e] = p;
  }
}

// ---- k_conv: persistent edge-parallel, 3-STAGE pipeline -------------------
// LOAD(n+2) || TRIG(n+1) || COMPUTE(n): index/pos loads get two compute
// periods of latency cover. cb/sb tables in LDS (R7-proven), w1 in regs.
// (256,2): no spill (R6 lesson: tighter bounds spill acc -> 208MB HBM).
__global__ __launch_bounds__(256, 2) void k_conv(
    const int* __restrict__ ei, int E, int eTot,
    const float* __restrict__ posp,
    const float* __restrict__ tN, const float* __restrict__ dN,
    const float* __restrict__ kw0, const float* __restrict__ kb0,
    const _Float16* __restrict__ bC, const _Float16* __restrict__ bS,
    const _Float16* __restrict__ w1f, const float* __restrict__ b1,
    const int* __restrict__ inv, float* __restrict__ msg) {
  __shared__ __attribute__((aligned(16))) _Float16 bCs[4096], bSs[4096];
  __shared__ __attribute__((aligned(16))) _Float16 scS[4][2][64], scC[4][2][64];
  const int tid = threadIdx.x;
  const int wave = __builtin_amdgcn_readfirstlane(tid >> 6), lane = tid & 63;
  const int q = lane >> 4;
  for (int idx = tid; idx < 512; idx += 256) {
    ((f16x8*)bCs)[idx] = ((const f16x8*)bC)[idx];
    ((f16x8*)bSs)[idx] = ((const f16x8*)bS)[idx];
  }
  f16x8 w1r[8];
#pragma unroll
  for (int f = 0; f < 8; ++f) w1r[f] = *(const f16x8*)(w1f + ((f << 6) + lane) * 8);
  f32x4 bbq[4];  // accumulator init = 0.1*b1[k]
#pragma unroll
  for (int ms = 0; ms < 4; ++ms) {
    f32x4 t = *(const f32x4*)(b1 + ms * 16 + q * 4);
    bbq[ms] = t * 0.1f;
  }
  const float kb0v = kb0[lane];
  const float kw0x = kw0[lane], kw0y = kw0[HC + lane], kw0z = kw0[2 * HC + lane];
  __syncthreads();

  const int nW = gridDim.x * 4;
  const int e0 = blockIdx.x * 4 + wave;
  if (e0 >= eTot) return;

  struct St { int s; float px, py, pz, qx, qy, qz, dv; int ip; };
  auto loadA = [&](int ee, St& st) {
    int s, d2;
    if (ee < E) { s = ei[ee]; d2 = ei[E + ee]; } else { s = ee - E; d2 = s; }
    st.s = s;
    st.px = posp[s * 3]; st.py = posp[s * 3 + 1]; st.pz = posp[s * 3 + 2];
    st.qx = posp[d2 * 3]; st.qy = posp[d2 * 3 + 1]; st.qz = posp[d2 * 3 + 2];
    st.dv = dN[s];
    st.ip = inv[ee];
  };
  auto trigB = [&](const St& st, int slot) {
    const float rx = st.qx - st.px, ry = st.qy - st.py, rz = st.qz - st.pz;
    float f0 = 0.f, f1 = 0.f, f2 = 0.f;
    if (!(rx == 0.f && ry == 0.f && rz == 0.f)) {
      const float PI_F = 3.14159265358979323846f;
      float rho = sqrtf(rx * rx + ry * ry + rz * rz);
      float th = atan2f(ry, rx);
      float ratio = fminf(1.f, fmaxf(-1.f, rz / rho));
      float ph = asinf(ratio);
      f0 = rho; f1 = th / PI_F; f2 = ph / PI_F;
    }
    float base = fmaf(f0, kw0x, fmaf(f1, kw0y, fmaf(f2, kw0z, kb0v)));
    float sv, cv;
    sincosf(0.1f * base, &sv, &cv);
    scS[wave][slot][lane] = (_Float16)sv;
    scC[wave][slot][lane] = (_Float16)cv;
  };

  St stA, stB, stC;
  loadA(e0, stA);
  trigB(stA, 0);
  f32x4 trCur[4];
  {
    const float* trp = tN + (size_t)stA.s * HC;
#pragma unroll
    for (int ms = 0; ms < 4; ++ms) trCur[ms] = *(const f32x4*)(trp + ms * 16 + q * 4);
  }
  bool hasB = (e0 + nW) < eTot;
  if (hasB) loadA(e0 + nW, stB);
  int e = e0, buf = 0;
  __builtin_amdgcn_wave_barrier();

  while (true) {
    const bool hasC = (e + 2 * nW) < eTot;
    if (hasC) loadA(e + 2 * nW, stC);       // longest-latency issue first
    f32x4 trNxt[4];
    if (hasB) {
      trigB(stB, buf ^ 1);                   // trig for n+1 into other slot
      const float* trp = tN + (size_t)stB.s * HC;
#pragma unroll
      for (int ms = 0; ms < 4; ++ms) trNxt[ms] = *(const f32x4*)(trp + ms * 16 + q * 4);
    }
    __builtin_amdgcn_wave_barrier();

    // COMPUTE edge n (slot buf)
    f32x4 acc[4][4];
#pragma unroll
    for (int ms = 0; ms < 4; ++ms)
#pragma unroll
      for (int nt = 0; nt < 4; ++nt) acc[ms][nt] = bbq[ms];
#pragma unroll
    for (int ks = 0; ks < 2; ++ks) {
      f16x8 sv8 = *(const f16x8*)&scS[wave][buf][ks * 32 + q * 8];
      f16x8 cv8 = *(const f16x8*)&scC[wave][buf][ks * 32 + q * 8];
      f16x8 bf[4];
#pragma unroll
      for (int nt = 0; nt < 4; ++nt) {
        f16x8 cb = *(const f16x8*)&bCs[((ks * 4 + nt) * 64 + lane) * 8];
        f16x8 sb = *(const f16x8*)&bSs[((ks * 4 + nt) * 64 + lane) * 8];
        bf[nt] = sv8 * cb + cv8 * sb;
      }
#pragma unroll
      for (int ms = 0; ms < 4; ++ms)
#pragma unroll
        for (int nt = 0; nt < 4; ++nt)
          acc[ms][nt] = __builtin_amdgcn_mfma_f32_16x16x32_f16(
              w1r[ks * 4 + ms], bf[nt], acc[ms][nt], 0, 0, 0);
    }

    float snt0 = 0.f, snt1 = 0.f, snt2 = 0.f, snt3 = 0.f;
#pragma unroll
    for (int ms = 0; ms < 4; ++ms) {
#pragma unroll
      for (int r = 0; r < 4; ++r) {
        float tt = trCur[ms][r];
        snt0 = fmaf(__sinf(acc[ms][0][r]), tt, snt0);
        snt1 = fmaf(__sinf(acc[ms][1][r]), tt, snt1);
        snt2 = fmaf(__sinf(acc[ms][2][r]), tt, snt2);
        snt3 = fmaf(__sinf(acc[ms][3][r]), tt, snt3);
      }
    }
    snt0 += __shfl_xor(snt0, 16, 64); snt0 += __shfl_xor(snt0, 32, 64);
    snt1 += __shfl_xor(snt1, 16, 64); snt1 += __shfl_xor(snt1, 32, 64);
    snt2 += __shfl_xor(snt2, 16, 64); snt2 += __shfl_xor(snt2, 32, 64);
    snt3 += __shfl_xor(snt3, 16, 64); snt3 += __shfl_xor(snt3, 32, 64);
    float val = (q == 0) ? snt0 : (q == 1) ? snt1 : (q == 2) ? snt2 : snt3;
    msg[(size_t)stA.ip * HC + lane] = val + stA.dv;

    if (!hasB) break;
    stA = stB;
    stB = stC;
#pragma unroll
    for (int ms = 0; ms < 4; ++ms) trCur[ms] = trNxt[ms];
    hasB = hasC;
    e += nW;
    buf ^= 1;
  }
}

// ---- CSR segment-sum (contiguous msg) + sin(0.01*(sum+bias)) ----------------
__global__ void k_reduce0(const float* __restrict__ msg, const int* __restrict__ rp,
                          const float* __restrict__ bias, float* __restrict__ hc) {
  const int wave = threadIdx.x >> 6, lane = threadIdx.x & 63;
  const int n = blockIdx.x * 4 + wave;
  const int j0 = rp[n], j1 = rp[n + 1];
  const float* p = msg + (size_t)j0 * HC + lane;
  const int m = j1 - j0;
  float a0 = 0.f, a1 = 0.f;
  int j = 0;
  for (; j + 1 < m; j += 2) {
    a0 += p[(size_t)j * HC];
    a1 += p[(size_t)(j + 1) * HC];
  }
  if (j < m) a0 += p[(size_t)j * HC];
  hc[(size_t)n * HC + lane] = sinf(0.01f * (a0 + a1 + bias[lane]));
}

// ---- k_pool1: CSR max over kept nodes + per-node t/d for level 1 ------------
__global__ void k_pool1(const float* __restrict__ hc0, const int* __restrict__ eidx,
                        const int* __restrict__ rp, const int* __restrict__ ei,
                        const int* __restrict__ keep, const float* __restrict__ ppos,
                        const float* __restrict__ c1w2, const float* __restrict__ c1b2,
                        float* __restrict__ tN, float* __restrict__ dN) {
  __shared__ float w2s[64][69];
  __shared__ float xr[4][64];
  const int tid = threadIdx.x;
  const int wave = __builtin_amdgcn_readfirstlane(tid >> 6), lane = tid & 63;
  for (int idx = tid; idx < HC * FC; idx += 256)
    w2s[idx / FC][idx % FC] = c1w2[idx];
  const int i = blockIdx.x * 4 + wave;
  int n = keep[i];
  int j0 = rp[n], j1 = rp[n + 1];
  float m = -INFINITY;
  for (int j = j0; j < j1; ++j) {
    int e = eidx[j];
    int src = (e < E0C) ? ei[e] : (e - E0C);
    m = fmaxf(m, hc0[(size_t)src * HC + lane]);
  }
  xr[wave][lane] = m;
  __syncthreads();
  const float px = ppos[i * 3], py = ppos[i * 3 + 1], pz = ppos[i * 3 + 2];
  float tl = 0.f, ds = 0.f;
#pragma unroll 8
  for (int f = 0; f < HC; ++f) {
    float xv = xr[wave][f];
    tl = fmaf(xv, w2s[lane][f], tl);
    ds = fmaf(xv, c1b2[f], ds);
  }
  tl = fmaf(px, w2s[lane][64], fmaf(py, w2s[lane][65], fmaf(pz, w2s[lane][66], tl)));
  ds = fmaf(px, c1b2[64], fmaf(py, c1b2[65], fmaf(pz, c1b2[66], ds)));
  tN[i * HC + lane] = tl;
  if (lane == 0) dN[i] = ds;
}

// ---- reduce level-1 (contiguous msg) + final linear + sin -------------------
__global__ void k_reduce1f(const float* __restrict__ msg, const int* __restrict__ rp,
                           const float* __restrict__ bias, const float* __restrict__ l1w,
                           const float* __restrict__ l1b, float* __restrict__ outp) {
  __shared__ float hr[4][64];
  const int wave = threadIdx.x >> 6, lane = threadIdx.x & 63;
  const int node = blockIdx.x * 4 + wave;
  const int j0 = rp[node], j1 = rp[node + 1];
  const float* p = msg + (size_t)j0 * HC + lane;
  const int m = j1 - j0;
  float a0 = 0.f, a1 = 0.f;
  int j = 0;
  for (; j + 1 < m; j += 2) {
    a0 += p[(size_t)j * HC];
    a1 += p[(size_t)(j + 1) * HC];
  }
  if (j < m) a0 += p[(size_t)j * HC];
  hr[wave][lane] = sinf(0.01f * (a0 + a1 + bias[lane]));
  __syncthreads();
  if (lane < LATC) {
    const float* h = hr[wave];
    float o = l1b[lane];
#pragma unroll 8
    for (int c = 0; c < HC; ++c) o = fmaf(h[c], l1w[c * LATC + lane], o);
    outp[node * LATC + lane] = sinf(0.01f * o);
  }
}

extern "C" void kernel_launch(void* const* d_in, const int* in_sizes, int n_in,
                              void* d_out, int out_size, void* d_ws, size_t ws_size,
                              hipStream_t stream) {
  (void)in_sizes; (void)n_in; (void)out_size; (void)ws_size;
  const float* x    = (const float*)d_in[0];
  const float* pos  = (const float*)d_in[1];
  const int*   ei   = (const int*)d_in[2];
  const int*   pei  = (const int*)d_in[3];
  const float* ppos = (const float*)d_in[4];
  const int*   keep = (const int*)d_in[5];
  const float* l0w  = (const float*)d_in[6];
  const float* l0b  = (const float*)d_in[7];
  const float* l1w  = (const float*)d_in[8];
  const float* l1b  = (const float*)d_in[9];
  const float* c0w0 = (const float*)d_in[10];
  const float* c0b0 = (const float*)d_in[11];
  const float* c0w1 = (const float*)d_in[12];
  const float* c0b1 = (const float*)d_in[13];
  const float* c0w2 = (const float*)d_in[14];
  const float* c0b2 = (const float*)d_in[15];
  const float* c0bias = (const float*)d_in[16];
  const float* c1w0 = (const float*)d_in[17];
  const float* c1b0 = (const float*)d_in[18];
  const float* c1w1 = (const float*)d_in[19];
  const float* c1b1 = (const float*)d_in[20];
  const float* c1w2 = (const float*)d_in[21];
  const float* c1b2 = (const float*)d_in[22];
  const float* c1bias = (const float*)d_in[23];
  float* outp = (float*)d_out;

  char* p = (char*)d_ws;
  auto carve = [&](size_t bytes) -> char* {
    char* r = p;
    p += (bytes + 255) & ~(size_t)255;
    return r;
  };
  float* hc0  = (float*)carve((size_t)N0C * HC * 4);
  float* tN0  = (float*)carve((size_t)N0C * HC * 4);
  float* dN0  = (float*)carve((size_t)N0C * 4);
  float* tN1  = (float*)carve((size_t)N1C * HC * 4);
  float* dN1  = (float*)carve((size_t)N1C * 4);
  _Float16* bC0  = (_Float16*)carve(4096 * 2);
  _Float16* bS0  = (_Float16*)carve(4096 * 2);
  _Float16* bC1  = (_Float16*)carve(4096 * 2);
  _Float16* bS1  = (_Float16*)carve(4096 * 2);
  _Float16* w1f0 = (_Float16*)carve(4096 * 2);
  _Float16* w1f1 = (_Float16*)carve(4096 * 2);
  int* cnt  = (int*)carve((size_t)(N0C + N1C) * 4);  // cnt+fill contiguous
  int* fill = (int*)carve((size_t)(N0C + N1C) * 4);
  int* rp0 = (int*)carve((size_t)(N0C + 1) * 4);
  int* rp1 = (int*)carve((size_t)(N1C + 1) * 4);
  int* eidx0 = (int*)carve((size_t)E0T * 4);
  int* eidx1 = (int*)carve((size_t)E1T * 4);
  int* inv0  = (int*)carve((size_t)E0T * 4);
  int* inv1  = (int*)carve((size_t)E1T * 4);
  float* msg = (float*)carve((size_t)E0T * HC * 4);  // reused for level 1

  hipMemsetAsync(cnt, 0, (size_t)(N0C + N1C) * 4 * 2, stream);

  k_prep<<<256 + 180, 256, 0, stream>>>(x, l0w, l0b, pos, c0w2, c0b2,
                                        c0w0, c1w0, c0w1, c1w1, ei, pei,
                                        bC0, bS0, bC1, bS1, w1f0, w1f1,
                                        cnt, tN0, dN0);
  k_scan<<<2, 1024, 0, stream>>>(cnt, rp0, rp1);
  k_scatter<<<(E0T + E1T + 255) / 256, 256, 0, stream>>>(ei, pei, rp0, rp1, fill,
                                                         eidx0, eidx1, inv0, inv1);
  k_conv<<<512, 256, 0, stream>>>(ei, E0C, E0T, pos, tN0, dN0, c0w0, c0b0,
                                  bC0, bS0, w1f0, c0b1, inv0, msg);
  k_reduce0<<<N0C / 4, 256, 0, stream>>>(msg, rp0, c0bias, hc0);
  k_pool1<<<N1C / 4, 256, 0, stream>>>(hc0, eidx0, rp0, ei, keep, ppos,
                                       c1w2, c1b2, tN1, dN1);
  k_conv<<<512, 256, 0, stream>>>(pei, E1C, E1T, ppos, tN1, dN1, c1w0, c1b0,
                                  bC1, bS1, w1f1, c1b1, inv1, msg);
  k_reduce1f<<<N1C / 4, 256, 0, stream>>>(msg, rp1, c1bias, l1w, l1b, outp);
}

// Round 12
// 180.769 us; speedup vs baseline: 2.0406x; 1.0369x over previous
//
#include <hip/hip_runtime.h>
#include <hip/hip_fp16.h>

// Problem constants (from reference)
#define N0C 4096
#define E0C 16384
#define N1C 1024
#define E1C 8192
#define HC 64
#define FINC 8
#define LATC 32
#define FC 67
#define E0T (E0C + N0C)
#define E1T (E1C + N1C)

typedef float f32x4 __attribute__((ext_vector_type(4)));
typedef _Float16 f16x8 __attribute__((ext_vector_type(8)));

// ---- k_prep: blocks [0,256): encoder + per-node t/d (level 0, 4 nodes/wave)
//              blocks [256,436): basis+w1 frag packing (fp16) + degree count
__global__ __launch_bounds__(256) void k_prep(
    const float* __restrict__ x, const float* __restrict__ l0w,
    const float* __restrict__ l0b, const float* __restrict__ posp,
    const float* __restrict__ c0w2, const float* __restrict__ c0b2,
    const float* __restrict__ c0w0, const float* __restrict__ c1w0,
    const float* __restrict__ c0w1, const float* __restrict__ c1w1,
    const int* __restrict__ ei0, const int* __restrict__ ei1,
    _Float16* __restrict__ bC0, _Float16* __restrict__ bS0,
    _Float16* __restrict__ bC1, _Float16* __restrict__ bS1,
    _Float16* __restrict__ w1f0, _Float16* __restrict__ w1f1,
    int* __restrict__ cnt, float* __restrict__ tN, float* __restrict__ dN) {
  if (blockIdx.x < 256) {
    __shared__ float w2s[64][69];  // pad 67->69
    __shared__ float xr[4][64];
    const int tid = threadIdx.x;
    const int wave = __builtin_amdgcn_readfirstlane(tid >> 6), lane = tid & 63;
    for (int idx = tid; idx < HC * FC; idx += 256)
      w2s[idx / FC][idx % FC] = c0w2[idx];
    __syncthreads();
#pragma unroll
    for (int i = 0; i < 4; ++i) {
      const int n = (blockIdx.x * 4 + wave) + i * 1024;
      float a = l0b[lane];
#pragma unroll
      for (int f = 0; f < FINC; ++f) a = fmaf(x[n * FINC + f], l0w[f * HC + lane], a);
      xr[wave][lane] = sinf(0.01f * a);
      __builtin_amdgcn_wave_barrier();
      const float px = posp[n * 3], py = posp[n * 3 + 1], pz = posp[n * 3 + 2];
      float tl = 0.f, ds = 0.f;
#pragma unroll 8
      for (int f = 0; f < HC; ++f) {
        float xv = xr[wave][f];
        tl = fmaf(xv, w2s[lane][f], tl);
        ds = fmaf(xv, c0b2[f], ds);
      }
      tl = fmaf(px, w2s[lane][64], fmaf(py, w2s[lane][65], fmaf(pz, w2s[lane][66], tl)));
      ds = fmaf(px, c0b2[64], fmaf(py, c0b2[65], fmaf(pz, c0b2[66], ds)));
      tN[n * HC + lane] = tl;
      if (lane == 0) dN[n] = ds;
      __builtin_amdgcn_wave_barrier();
    }
  } else {
    int id = (blockIdx.x - 256) * 256 + threadIdx.x;
    if (id < 8192) {  // basis frags: r=((ks*4+nt)*64+lane)*8+j
      int lvl = id >> 12, r = id & 4095;
      int fi = r >> 9, lane = (r >> 3) & 63, j = r & 7;
      int nt = fi & 3, ks = fi >> 2;
      int c = nt * 16 + (lane & 15);
      int h = ks * 32 + (lane >> 4) * 8 + j;
      const float* w = lvl ? c1w0 : c0w0;
      float s, cv;
      sincosf(0.1f * (float)c * w[3 * HC + h], &s, &cv);
      (lvl ? bC1 : bC0)[r] = (_Float16)cv;
      (lvl ? bS1 : bS0)[r] = (_Float16)s;
    } else if (id < 16384) {  // w1 frags (pre-scaled by 0.1)
      int r0 = id - 8192;
      int lvl = r0 >> 12, r = r0 & 4095;
      int fi = r >> 9, lane = (r >> 3) & 63, j = r & 7;
      int ms = fi & 3, ks = fi >> 2;
      int h = ks * 32 + (lane >> 4) * 8 + j;
      int kout = ms * 16 + (lane & 15);
      const float* w = lvl ? c1w1 : c0w1;
      (lvl ? w1f1 : w1f0)[r] = (_Float16)(0.1f * w[h * HC + kout]);
    } else if (id < 16384 + E0T + E1T) {  // degree
      int r = id - 16384;
      if (r < E0T) {
        int dst = (r < E0C) ? ei0[E0C + r] : (r - E0C);
        atomicAdd(cnt + dst, 1);
      } else {
        int e = r - E0T;
        int dst = (e < E1C) ? ei1[E1C + e] : (e - E1C);
        atomicAdd(cnt + N0C + dst, 1);
      }
    }
  }
}

// ---- CSR scan, shfl-based (block 0: level0, block 1: level1) ----------------
__global__ void k_scan(const int* __restrict__ cnt, int* __restrict__ rp0,
                       int* __restrict__ rp1) {
  __shared__ int wsum[16];
  const int b = blockIdx.x;
  const int n = b ? N1C : N0C;
  const int* c = cnt + (b ? N0C : 0);
  int* rp = b ? rp1 : rp0;
  const int tid = threadIdx.x;
  const int lane = tid & 63, wid = tid >> 6;
  const int per = n >> 10;
  int loc[4];
  int sum = 0;
  for (int j = 0; j < per; ++j) { loc[j] = c[tid * per + j]; sum += loc[j]; }
  int xv = sum;
#pragma unroll
  for (int off = 1; off < 64; off <<= 1) {
    int v = __shfl_up(xv, off, 64);
    if (lane >= off) xv += v;
  }
  if (lane == 63) wsum[wid] = xv;
  __syncthreads();
  if (wid == 0) {
    int w = (lane < 16) ? wsum[lane] : 0;
#pragma unroll
    for (int off = 1; off < 16; off <<= 1) {
      int v = __shfl_up(w, off, 64);
      if (lane >= off) w += v;
    }
    if (lane < 16) wsum[lane] = w;
  }
  __syncthreads();
  int prefix = wid ? wsum[wid - 1] : 0;
  int incl = xv + prefix;
  int base = incl - sum;
  for (int j = 0; j < per; ++j) { rp[tid * per + j] = base; base += loc[j]; }
  if (tid == 1023) rp[n] = incl;
}

// ---- CSR scatter (also emits inverse permutation) ---------------------------
__global__ void k_scatter(const int* __restrict__ ei0, const int* __restrict__ ei1,
                          const int* __restrict__ rp0, const int* __restrict__ rp1,
                          int* __restrict__ fill, int* __restrict__ eidx0,
                          int* __restrict__ eidx1, int* __restrict__ inv0,
                          int* __restrict__ inv1) {
  int id = blockIdx.x * blockDim.x + threadIdx.x;
  if (id < E0T) {
    int dst = (id < E0C) ? ei0[E0C + id] : (id - E0C);
    int p = rp0[dst] + atomicAdd(fill + dst, 1);
    eidx0[p] = id;
    inv0[id] = p;
  } else if (id < E0T + E1T) {
    int e = id - E0T;
    int dst = (e < E1C) ? ei1[E1C + e] : (e - E1C);
    int p = rp1[dst] + atomicAdd(fill + N0C + dst, 1);
    eidx1[p] = e;
    inv1[e] = p;
  }
}

// ---- k_conv: persistent edge-parallel, pipelined; msg stored in CSR order ---
// Best-measured config (180.9us total): (256,3) = 84 VGPR no spill, LDS
// cb/sb tables, 2-stage pipeline, persistent grid 1536/768.
__global__ __launch_bounds__(256, 3) void k_conv(
    const int* __restrict__ ei, int E, int eTot,
    const float* __restrict__ posp,
    const float* __restrict__ tN, const float* __restrict__ dN,
    const float* __restrict__ kw0, const float* __restrict__ kb0,
    const _Float16* __restrict__ bC, const _Float16* __restrict__ bS,
    const _Float16* __restrict__ w1f, const float* __restrict__ b1,
    const int* __restrict__ inv, float* __restrict__ msg) {
  __shared__ __attribute__((aligned(16))) _Float16 bCs[4096], bSs[4096];
  __shared__ __attribute__((aligned(16))) _Float16 scS[4][2][64], scC[4][2][64];
  const int tid = threadIdx.x;
  const int wave = __builtin_amdgcn_readfirstlane(tid >> 6), lane = tid & 63;
  const int q = lane >> 4;
  for (int idx = tid; idx < 512; idx += 256) {
    ((f16x8*)bCs)[idx] = ((const f16x8*)bC)[idx];
    ((f16x8*)bSs)[idx] = ((const f16x8*)bS)[idx];
  }
  f16x8 w1r[8];
#pragma unroll
  for (int f = 0; f < 8; ++f) w1r[f] = *(const f16x8*)(w1f + ((f << 6) + lane) * 8);
  f32x4 bbq[4];  // accumulator init = 0.1*b1[k]
#pragma unroll
  for (int ms = 0; ms < 4; ++ms) {
    f32x4 t = *(const f32x4*)(b1 + ms * 16 + q * 4);
    bbq[ms] = t * 0.1f;
  }
  const float kb0v = kb0[lane];
  const float kw0x = kw0[lane], kw0y = kw0[HC + lane], kw0z = kw0[2 * HC + lane];
  __syncthreads();

  const int nW = gridDim.x * 4;
  int e = blockIdx.x * 4 + wave;
  if (e >= eTot) return;

  auto stg = [&](int ee, int& sN, float& sv, float& cv, float& dv) {
    int s, d2;
    if (ee < E) { s = ei[ee]; d2 = ei[E + ee]; } else { s = ee - E; d2 = s; }
    sN = s;
    const float px = posp[s * 3], py = posp[s * 3 + 1], pz = posp[s * 3 + 2];
    const float rx = posp[d2 * 3] - px;
    const float ry = posp[d2 * 3 + 1] - py;
    const float rz = posp[d2 * 3 + 2] - pz;
    float f0 = 0.f, f1 = 0.f, f2 = 0.f;
    if (!(rx == 0.f && ry == 0.f && rz == 0.f)) {
      const float PI_F = 3.14159265358979323846f;
      float rho = sqrtf(rx * rx + ry * ry + rz * rz);
      float th = atan2f(ry, rx);
      float ratio = fminf(1.f, fmaxf(-1.f, rz / rho));
      float ph = asinf(ratio);
      f0 = rho; f1 = th / PI_F; f2 = ph / PI_F;
    }
    float base = fmaf(f0, kw0x, fmaf(f1, kw0y, fmaf(f2, kw0z, kb0v)));
    sincosf(0.1f * base, &sv, &cv);
    dv = dN[s];
  };

  int s0;
  float sv0, cv0, dv0;
  stg(e, s0, sv0, cv0, dv0);
  int buf = 0;
  scS[wave][0][lane] = (_Float16)sv0;
  scC[wave][0][lane] = (_Float16)cv0;
  __builtin_amdgcn_wave_barrier();

  while (true) {
    const int en = e + nW;
    const bool more = en < eTot;
    // prefetch t-row + inv for current edge
    f32x4 tr[4];
    {
      const float* trp = tN + (size_t)s0 * HC;
#pragma unroll
      for (int ms = 0; ms < 4; ++ms) tr[ms] = *(const f32x4*)(trp + ms * 16 + q * 4);
    }
    const int ip = inv[e];
    // stage next edge (loads + trig) before compute of current
    int s1 = 0;
    float sv1 = 0.f, cv1 = 0.f, dv1 = 0.f;
    if (more) {
      stg(en, s1, sv1, cv1, dv1);
      scS[wave][buf ^ 1][lane] = (_Float16)sv1;
      scC[wave][buf ^ 1][lane] = (_Float16)cv1;
    }
    __builtin_amdgcn_wave_barrier();

    f32x4 acc[4][4];
#pragma unroll
    for (int ms = 0; ms < 4; ++ms)
#pragma unroll
      for (int nt = 0; nt < 4; ++nt) acc[ms][nt] = bbq[ms];
#pragma unroll
    for (int ks = 0; ks < 2; ++ks) {
      f16x8 sv8 = *(const f16x8*)&scS[wave][buf][ks * 32 + q * 8];
      f16x8 cv8 = *(const f16x8*)&scC[wave][buf][ks * 32 + q * 8];
      f16x8 bf[4];
#pragma unroll
      for (int nt = 0; nt < 4; ++nt) {
        f16x8 cb = *(const f16x8*)&bCs[((ks * 4 + nt) * 64 + lane) * 8];
        f16x8 sb = *(const f16x8*)&bSs[((ks * 4 + nt) * 64 + lane) * 8];
        bf[nt] = sv8 * cb + cv8 * sb;
      }
#pragma unroll
      for (int ms = 0; ms < 4; ++ms)
#pragma unroll
        for (int nt = 0; nt < 4; ++nt)
          acc[ms][nt] = __builtin_amdgcn_mfma_f32_16x16x32_f16(
              w1r[ks * 4 + ms], bf[nt], acc[ms][nt], 0, 0, 0);
    }

    // epilogue: reg r of acc[ms][nt] = 0.1*(z+b1) at [k=ms*16+q*4+r][c=nt*16+m]
    float snt0 = 0.f, snt1 = 0.f, snt2 = 0.f, snt3 = 0.f;
#pragma unroll
    for (int ms = 0; ms < 4; ++ms) {
#pragma unroll
      for (int r = 0; r < 4; ++r) {
        float tt = tr[ms][r];
        snt0 = fmaf(__sinf(acc[ms][0][r]), tt, snt0);
        snt1 = fmaf(__sinf(acc[ms][1][r]), tt, snt1);
        snt2 = fmaf(__sinf(acc[ms][2][r]), tt, snt2);
        snt3 = fmaf(__sinf(acc[ms][3][r]), tt, snt3);
      }
    }
    snt0 += __shfl_xor(snt0, 16, 64); snt0 += __shfl_xor(snt0, 32, 64);
    snt1 += __shfl_xor(snt1, 16, 64); snt1 += __shfl_xor(snt1, 32, 64);
    snt2 += __shfl_xor(snt2, 16, 64); snt2 += __shfl_xor(snt2, 32, 64);
    snt3 += __shfl_xor(snt3, 16, 64); snt3 += __shfl_xor(snt3, 32, 64);
    float val = (q == 0) ? snt0 : (q == 1) ? snt1 : (q == 2) ? snt2 : snt3;
    msg[(size_t)ip * HC + lane] = val + dv0;

    if (!more) break;
    e = en; s0 = s1; dv0 = dv1; buf ^= 1;
  }
}

// ---- CSR segment-sum (contiguous msg) + sin(0.01*(sum+bias)) ----------------
__global__ void k_reduce0(const float* __restrict__ msg, const int* __restrict__ rp,
                          const float* __restrict__ bias, float* __restrict__ hc) {
  const int wave = threadIdx.x >> 6, lane = threadIdx.x & 63;
  const int n = blockIdx.x * 4 + wave;
  const int j0 = rp[n], j1 = rp[n + 1];
  const float* p = msg + (size_t)j0 * HC + lane;
  const int m = j1 - j0;
  float a0 = 0.f, a1 = 0.f;
  int j = 0;
  for (; j + 1 < m; j += 2) {
    a0 += p[(size_t)j * HC];
    a1 += p[(size_t)(j + 1) * HC];
  }
  if (j < m) a0 += p[(size_t)j * HC];
  hc[(size_t)n * HC + lane] = sinf(0.01f * (a0 + a1 + bias[lane]));
}

// ---- k_pool1: CSR max over kept nodes + per-node t/d for level 1 ------------
__global__ void k_pool1(const float* __restrict__ hc0, const int* __restrict__ eidx,
                        const int* __restrict__ rp, const int* __restrict__ ei,
                        const int* __restrict__ keep, const float* __restrict__ ppos,
                        const float* __restrict__ c1w2, const float* __restrict__ c1b2,
                        float* __restrict__ tN, float* __restrict__ dN) {
  __shared__ float w2s[64][69];
  __shared__ float xr[4][64];
  const int tid = threadIdx.x;
  const int wave = __builtin_amdgcn_readfirstlane(tid >> 6), lane = tid & 63;
  for (int idx = tid; idx < HC * FC; idx += 256)
    w2s[idx / FC][idx % FC] = c1w2[idx];
  const int i = blockIdx.x * 4 + wave;
  int n = keep[i];
  int j0 = rp[n], j1 = rp[n + 1];
  float m = -INFINITY;
  for (int j = j0; j < j1; ++j) {
    int e = eidx[j];
    int src = (e < E0C) ? ei[e] : (e - E0C);
    m = fmaxf(m, hc0[(size_t)src * HC + lane]);
  }
  xr[wave][lane] = m;
  __syncthreads();
  const float px = ppos[i * 3], py = ppos[i * 3 + 1], pz = ppos[i * 3 + 2];
  float tl = 0.f, ds = 0.f;
#pragma unroll 8
  for (int f = 0; f < HC; ++f) {
    float xv = xr[wave][f];
    tl = fmaf(xv, w2s[lane][f], tl);
    ds = fmaf(xv, c1b2[f], ds);
  }
  tl = fmaf(px, w2s[lane][64], fmaf(py, w2s[lane][65], fmaf(pz, w2s[lane][66], tl)));
  ds = fmaf(px, c1b2[64], fmaf(py, c1b2[65], fmaf(pz, c1b2[66], ds)));
  tN[i * HC + lane] = tl;
  if (lane == 0) dN[i] = ds;
}

// ---- reduce level-1 (contiguous msg) + final linear + sin -------------------
__global__ void k_reduce1f(const float* __restrict__ msg, const int* __restrict__ rp,
                           const float* __restrict__ bias, const float* __restrict__ l1w,
                           const float* __restrict__ l1b, float* __restrict__ outp) {
  __shared__ float hr[4][64];
  const int wave = threadIdx.x >> 6, lane = threadIdx.x & 63;
  const int node = blockIdx.x * 4 + wave;
  const int j0 = rp[node], j1 = rp[node + 1];
  const float* p = msg + (size_t)j0 * HC + lane;
  const int m = j1 - j0;
  float a0 = 0.f, a1 = 0.f;
  int j = 0;
  for (; j + 1 < m; j += 2) {
    a0 += p[(size_t)j * HC];
    a1 += p[(size_t)(j + 1) * HC];
  }
  if (j < m) a0 += p[(size_t)j * HC];
  hr[wave][lane] = sinf(0.01f * (a0 + a1 + bias[lane]));
  __syncthreads();
  if (lane < LATC) {
    const float* h = hr[wave];
    float o = l1b[lane];
#pragma unroll 8
    for (int c = 0; c < HC; ++c) o = fmaf(h[c], l1w[c * LATC + lane], o);
    outp[node * LATC + lane] = sinf(0.01f * o);
  }
}

extern "C" void kernel_launch(void* const* d_in, const int* in_sizes, int n_in,
                              void* d_out, int out_size, void* d_ws, size_t ws_size,
                              hipStream_t stream) {
  (void)in_sizes; (void)n_in; (void)out_size; (void)ws_size;
  const float* x    = (const float*)d_in[0];
  const float* pos  = (const float*)d_in[1];
  const int*   ei   = (const int*)d_in[2];
  const int*   pei  = (const int*)d_in[3];
  const float* ppos = (const float*)d_in[4];
  const int*   keep = (const int*)d_in[5];
  const float* l0w  = (const float*)d_in[6];
  const float* l0b  = (const float*)d_in[7];
  const float* l1w  = (const float*)d_in[8];
  const float* l1b  = (const float*)d_in[9];
  const float* c0w0 = (const float*)d_in[10];
  const float* c0b0 = (const float*)d_in[11];
  const float* c0w1 = (const float*)d_in[12];
  const float* c0b1 = (const float*)d_in[13];
  const float* c0w2 = (const float*)d_in[14];
  const float* c0b2 = (const float*)d_in[15];
  const float* c0bias = (const float*)d_in[16];
  const float* c1w0 = (const float*)d_in[17];
  const float* c1b0 = (const float*)d_in[18];
  const float* c1w1 = (const float*)d_in[19];
  const float* c1b1 = (const float*)d_in[20];
  const float* c1w2 = (const float*)d_in[21];
  const float* c1b2 = (const float*)d_in[22];
  const float* c1bias = (const float*)d_in[23];
  float* outp = (float*)d_out;

  char* p = (char*)d_ws;
  auto carve = [&](size_t bytes) -> char* {
    char* r = p;
    p += (bytes + 255) & ~(size_t)255;
    return r;
  };
  float* hc0  = (float*)carve((size_t)N0C * HC * 4);
  float* tN0  = (float*)carve((size_t)N0C * HC * 4);
  float* dN0  = (float*)carve((size_t)N0C * 4);
  float* tN1  = (float*)carve((size_t)N1C * HC * 4);
  float* dN1  = (float*)carve((size_t)N1C * 4);
  _Float16* bC0  = (_Float16*)carve(4096 * 2);
  _Float16* bS0  = (_Float16*)carve(4096 * 2);
  _Float16* bC1  = (_Float16*)carve(4096 * 2);
  _Float16* bS1  = (_Float16*)carve(4096 * 2);
  _Float16* w1f0 = (_Float16*)carve(4096 * 2);
  _Float16* w1f1 = (_Float16*)carve(4096 * 2);
  int* cnt  = (int*)carve((size_t)(N0C + N1C) * 4);  // cnt+fill contiguous
  int* fill = (int*)carve((size_t)(N0C + N1C) * 4);
  int* rp0 = (int*)carve((size_t)(N0C + 1) * 4);
  int* rp1 = (int*)carve((size_t)(N1C + 1) * 4);
  int* eidx0 = (int*)carve((size_t)E0T * 4);
  int* eidx1 = (int*)carve((size_t)E1T * 4);
  int* inv0  = (int*)carve((size_t)E0T * 4);
  int* inv1  = (int*)carve((size_t)E1T * 4);
  float* msg = (float*)carve((size_t)E0T * HC * 4);  // reused for level 1

  hipMemsetAsync(cnt, 0, (size_t)(N0C + N1C) * 4 * 2, stream);

  k_prep<<<256 + 180, 256, 0, stream>>>(x, l0w, l0b, pos, c0w2, c0b2,
                                        c0w0, c1w0, c0w1, c1w1, ei, pei,
                                        bC0, bS0, bC1, bS1, w1f0, w1f1,
                                        cnt, tN0, dN0);
  k_scan<<<2, 1024, 0, stream>>>(cnt, rp0, rp1);
  k_scatter<<<(E0T + E1T + 255) / 256, 256, 0, stream>>>(ei, pei, rp0, rp1, fill,
                                                         eidx0, eidx1, inv0, inv1);
  k_conv<<<1536, 256, 0, stream>>>(ei, E0C, E0T, pos, tN0, dN0, c0w0, c0b0,
                                   bC0, bS0, w1f0, c0b1, inv0, msg);
  k_reduce0<<<N0C / 4, 256, 0, stream>>>(msg, rp0, c0bias, hc0);
  k_pool1<<<N1C / 4, 256, 0, stream>>>(hc0, eidx0, rp0, ei, keep, ppos,
                                       c1w2, c1b2, tN1, dN1);
  k_conv<<<768, 256, 0, stream>>>(pei, E1C, E1T, ppos, tN1, dN1, c1w0, c1b0,
                                  bC1, bS1, w1f1, c1b1, inv1, msg);
  k_reduce1f<<<N1C / 4, 256, 0, stream>>>(msg, rp1, c1bias, l1w, l1b, outp);
}